// Round 2
// baseline (1777.448 us; speedup 1.0000x reference)
//
#include <hip/hip_runtime.h>
#include <math.h>

#define HEADS 4
#define CH 64
#define HC 256   // HEADS*CH
#define NPB 8    // nodes per block in feat_kernel

// ---------------------------------------------------------------------------
__device__ __forceinline__ void atomicMaxFloat(float* addr, float val) {
    if (val >= 0.0f) {
        atomicMax((int*)addr, __float_as_int(val));
    } else {
        atomicMin((unsigned int*)addr, __float_as_uint(val));
    }
}

__device__ __forceinline__ float lrelu(float v) {
    return v > 0.f ? v : 0.2f * v;
}

// ---------------------------------------------------------------------------
// Per-node transform: hbuf[n,0:256] = in[n,0:K] @ W[K,256], plus logits.
// 8 nodes per block so each W element is loaded once per 8 nodes.
__global__ void feat_kernel(const float* __restrict__ in, int K,
                            const float* __restrict__ W,
                            const float* __restrict__ a_src,
                            const float* __restrict__ a_dst,
                            float* __restrict__ hbuf,
                            float* __restrict__ asrc,
                            float* __restrict__ adst, int N) {
    __shared__ float xrow[NPB][64];
    int t = threadIdx.x;
    int base = blockIdx.x * NPB;
    for (int i = t; i < NPB * K; i += 256) {
        int nb = i / K, k = i - nb * K;
        int n = base + nb;
        if (n < N) xrow[nb][k] = in[(size_t)n * K + k];
    }
    __syncthreads();
    float acc[NPB];
#pragma unroll
    for (int nb = 0; nb < NPB; ++nb) acc[nb] = 0.f;
    for (int k = 0; k < K; ++k) {
        float w = W[k * HC + t];
#pragma unroll
        for (int nb = 0; nb < NPB; ++nb) acc[nb] += xrow[nb][k] * w;
    }
    int head = t >> 6, lane = t & 63;
    float aw_s = a_src[t], aw_d = a_dst[t];
#pragma unroll
    for (int nb = 0; nb < NPB; ++nb) {
        int n = base + nb;
        if (n >= N) break;
        hbuf[(size_t)n * HC + t] = acc[nb];
        float vs = acc[nb] * aw_s, vd = acc[nb] * aw_d;
        for (int off = 32; off; off >>= 1) {
            vs += __shfl_down(vs, off);
            vd += __shfl_down(vd, off);
        }
        if (lane == 0) {
            asrc[n * HEADS + head] = vs;
            adst[n * HEADS + head] = vd;
        }
    }
}

// ---------------------------------------------------------------------------
// acc=0 over N*64; emax=-inf, denom=0 over N*4
__global__ void init_kernel(float* __restrict__ emax,
                            float* __restrict__ denom,
                            float* __restrict__ acc, int N) {
    int i = blockIdx.x * blockDim.x + threadIdx.x;
    if (i < N * HEADS) { emax[i] = -INFINITY; denom[i] = 0.f; }
    if (i < N * CH) acc[i] = 0.f;
}

// ---------------------------------------------------------------------------
// Pass A: one thread per edge, all 4 heads. ev[e,:] = leaky_relu(as[s]+ad[d]);
// store ev (linear float4), atomicMax into emax[d,:].
__global__ void edge_logits_kernel(const int* __restrict__ src,
                                   const int* __restrict__ dst,
                                   int E, int N,
                                   const float4* __restrict__ asrc4,
                                   const float4* __restrict__ adst4,
                                   float4* __restrict__ ev4,
                                   float* __restrict__ emax) {
    int e = blockIdx.x * blockDim.x + threadIdx.x;
    if (e >= E + N) return;
    int s, d;
    if (e < E) { s = src[e]; d = dst[e]; } else { s = d = e - E; }
    float4 as = asrc4[s], ad = adst4[d];
    float4 ev;
    ev.x = lrelu(as.x + ad.x);
    ev.y = lrelu(as.y + ad.y);
    ev.z = lrelu(as.z + ad.z);
    ev.w = lrelu(as.w + ad.w);
    ev4[e] = ev;
    float* em = &emax[d * HEADS];
    atomicMaxFloat(em + 0, ev.x);
    atomicMaxFloat(em + 1, ev.y);
    atomicMaxFloat(em + 2, ev.z);
    atomicMaxFloat(em + 3, ev.w);
}

// Pass B: ex[e,:] = exp(ev - emax[d,:]); store ex in place; denom[d,:] += ex.
__global__ void edge_exp_kernel(const int* __restrict__ dst,
                                int E, int N,
                                float4* __restrict__ ev4,
                                const float4* __restrict__ emax4,
                                float* __restrict__ denom) {
    int e = blockIdx.x * blockDim.x + threadIdx.x;
    if (e >= E + N) return;
    int d = (e < E) ? dst[e] : e - E;
    float4 ev = ev4[e];
    float4 m = emax4[d];
    float4 ex;
    ex.x = expf(ev.x - m.x);
    ex.y = expf(ev.y - m.y);
    ex.z = expf(ev.z - m.z);
    ex.w = expf(ev.w - m.w);
    ev4[e] = ex;
    float* dn = &denom[d * HEADS];
    atomicAdd(dn + 0, ex.x);
    atomicAdd(dn + 1, ex.y);
    atomicAdd(dn + 2, ex.z);
    atomicAdd(dn + 3, ex.w);
}

// denom -> 1/denom
__global__ void recip_kernel(float* __restrict__ denom, int n) {
    int i = blockIdx.x * blockDim.x + threadIdx.x;
    if (i < n) denom[i] = 1.f / denom[i];
}

// ---------------------------------------------------------------------------
// Pass C: wave per edge, lane = channel.
// acc[d,c] += sum_h hbuf[s,h,c] * (ex[e,h] * inv_denom[d,h])
__global__ void edge_agg_kernel(const int* __restrict__ src,
                                const int* __restrict__ dst,
                                int E, int N,
                                const float4* __restrict__ ex4,
                                const float4* __restrict__ invden4,
                                const float* __restrict__ hbuf,
                                float* __restrict__ acc) {
    long long gid = (long long)blockIdx.x * blockDim.x + threadIdx.x;
    long long total = (long long)(E + N) * 64;
    if (gid >= total) return;
    int e = (int)(gid >> 6);
    int c = (int)(gid & 63);
    int s, d;
    if (e < E) { s = src[e]; d = dst[e]; } else { s = d = e - E; }
    float4 ex = ex4[e];
    float4 iv = invden4[d];
    float w0 = ex.x * iv.x, w1 = ex.y * iv.y, w2 = ex.z * iv.z, w3 = ex.w * iv.w;
    const float* hp = hbuf + (size_t)s * HC + c;
    float sum = hp[0] * w0 + hp[CH] * w1 + hp[2 * CH] * w2 + hp[3 * CH] * w3;
    atomicAdd(&acc[(size_t)d * CH + c], sum);
}

// ---------------------------------------------------------------------------
__global__ void postproc_kernel(float* __restrict__ acc,
                                const float* __restrict__ b,
                                const float* __restrict__ residual,
                                int N) {
    int i = blockIdx.x * blockDim.x + threadIdx.x;
    if (i >= N * CH) return;
    int c = i & 63;
    float v = acc[i] * (1.0f / HEADS) + b[c];
    v = v > 0.f ? v : expm1f(v);
    if (residual) v += residual[i];
    acc[i] = v;
}

// ---------------------------------------------------------------------------
__global__ void final_kernel(const float* __restrict__ h3,
                             const float* __restrict__ lin_w,
                             const float* __restrict__ lin_b,
                             float* __restrict__ out, int N) {
    long long gid = (long long)blockIdx.x * blockDim.x + threadIdx.x;
    if (gid >= (long long)N * 64) return;
    int n = (int)(gid >> 6);
    int lane = (int)(gid & 63);
    float v = h3[(size_t)n * CH + lane] * lin_w[lane];
    for (int off = 32; off; off >>= 1) v += __shfl_down(v, off);
    if (lane == 0) out[n] = v + lin_b[0];
}

// ---------------------------------------------------------------------------
extern "C" void kernel_launch(void* const* d_in, const int* in_sizes, int n_in,
                              void* d_out, int out_size, void* d_ws, size_t ws_size,
                              hipStream_t stream) {
    const float* x      = (const float*)d_in[0];
    const int*   ei     = (const int*)  d_in[1];
    const float* W1     = (const float*)d_in[2];
    const float* a1s    = (const float*)d_in[3];
    const float* a1d    = (const float*)d_in[4];
    const float* b1     = (const float*)d_in[5];
    const float* W2     = (const float*)d_in[6];
    const float* a2s    = (const float*)d_in[7];
    const float* a2d    = (const float*)d_in[8];
    const float* b2     = (const float*)d_in[9];
    const float* W3     = (const float*)d_in[10];
    const float* a3s    = (const float*)d_in[11];
    const float* a3d    = (const float*)d_in[12];
    const float* b3     = (const float*)d_in[13];
    const float* lin_w  = (const float*)d_in[14];
    const float* lin_b  = (const float*)d_in[15];

    const int N = in_sizes[0] / 3;
    const int E = in_sizes[1] / 2;
    const int Et = E + N;
    const int* src = ei;
    const int* dst = ei + E;

    float* ws    = (float*)d_ws;
    float* hbuf  = ws;                              // N*256
    float* asrc  = hbuf  + (size_t)N * HC;          // N*4
    float* adst  = asrc  + (size_t)N * HEADS;       // N*4
    float* emax  = adst  + (size_t)N * HEADS;       // N*4
    float* denom = emax  + (size_t)N * HEADS;       // N*4
    float* bufA  = denom + (size_t)N * HEADS;       // N*64 (h1)
    float* bufB  = bufA  + (size_t)N * CH;          // N*64 (h2)
    float* bufC  = bufB  + (size_t)N * CH;          // N*64 (h3)
    float* evbuf = bufC  + (size_t)N * CH;          // Et*4 (ev -> ex)

    const int B = 256;
    auto run_layer = [&](const float* inp, int K, const float* W,
                         const float* as, const float* ad, const float* bb,
                         const float* residual, float* outbuf) {
        feat_kernel<<<(N + NPB - 1) / NPB, B, 0, stream>>>(
            inp, K, W, as, ad, hbuf, asrc, adst, N);
        init_kernel<<<(N * CH + B - 1) / B, B, 0, stream>>>(emax, denom, outbuf, N);
        int e_blocks = (Et + B - 1) / B;
        edge_logits_kernel<<<e_blocks, B, 0, stream>>>(
            src, dst, E, N, (const float4*)asrc, (const float4*)adst,
            (float4*)evbuf, emax);
        edge_exp_kernel<<<e_blocks, B, 0, stream>>>(
            dst, E, N, (float4*)evbuf, (const float4*)emax, denom);
        recip_kernel<<<(N * HEADS + B - 1) / B, B, 0, stream>>>(denom, N * HEADS);
        long long agg_threads = (long long)Et * 64;
        edge_agg_kernel<<<(int)((agg_threads + B - 1) / B), B, 0, stream>>>(
            src, dst, E, N, (const float4*)evbuf, (const float4*)denom,
            hbuf, outbuf);
        postproc_kernel<<<(N * CH + B - 1) / B, B, 0, stream>>>(outbuf, bb, residual, N);
    };

    run_layer(x,    3,  W1, a1s, a1d, b1, nullptr, bufA);  // h1
    run_layer(bufA, 64, W2, a2s, a2d, b2, bufA,    bufB);  // h2 = elu(.)+h1
    run_layer(bufB, 64, W3, a3s, a3d, b3, bufB,    bufC);  // h3 = elu(.)+h2

    long long fin_threads = (long long)N * 64;
    final_kernel<<<(int)((fin_threads + B - 1) / B), B, 0, stream>>>(
        bufC, lin_w, lin_b, (float*)d_out, N);
}

// Round 3
// 828.880 us; speedup vs baseline: 2.1444x; 2.1444x over previous
//
#include <hip/hip_runtime.h>
#include <math.h>

#define HEADS 4
#define CH 64
#define HC 256   // HEADS*CH
#define NPB 8    // nodes per block in feat_kernel
#define SCAN_T 1024

__device__ __forceinline__ float lrelu(float v) { return v > 0.f ? v : 0.2f * v; }

// ---------------------------------------------------------------------------
// Per-node transform: hbuf[n,0:256] = in[n,0:K] @ W[K,256], plus logits.
__global__ void feat_kernel(const float* __restrict__ in, int K,
                            const float* __restrict__ W,
                            const float* __restrict__ a_src,
                            const float* __restrict__ a_dst,
                            float* __restrict__ hbuf,
                            float* __restrict__ asrc,
                            float* __restrict__ adst, int N) {
    __shared__ float xrow[NPB][64];
    int t = threadIdx.x;
    int base = blockIdx.x * NPB;
    for (int i = t; i < NPB * K; i += 256) {
        int nb = i / K, k = i - nb * K;
        int n = base + nb;
        if (n < N) xrow[nb][k] = in[(size_t)n * K + k];
    }
    __syncthreads();
    float acc[NPB];
#pragma unroll
    for (int nb = 0; nb < NPB; ++nb) acc[nb] = 0.f;
    for (int k = 0; k < K; ++k) {
        float w = W[k * HC + t];
#pragma unroll
        for (int nb = 0; nb < NPB; ++nb) acc[nb] += xrow[nb][k] * w;
    }
    int head = t >> 6, lane = t & 63;
    float aw_s = a_src[t], aw_d = a_dst[t];
#pragma unroll
    for (int nb = 0; nb < NPB; ++nb) {
        int n = base + nb;
        if (n >= N) break;
        hbuf[(size_t)n * HC + t] = acc[nb];
        float vs = acc[nb] * aw_s, vd = acc[nb] * aw_d;
        for (int off = 32; off; off >>= 1) {
            vs += __shfl_down(vs, off);
            vd += __shfl_down(vd, off);
        }
        if (lane == 0) {
            asrc[n * HEADS + head] = vs;
            adst[n * HEADS + head] = vd;
        }
    }
}

// ---------------------------------------------------------------------------
// CSR build (once per call; graph shared by all 3 layers)
__global__ void zero_int2(int* __restrict__ a, int* __restrict__ b, int n) {
    int i = blockIdx.x * blockDim.x + threadIdx.x;
    if (i < n) { a[i] = 0; b[i] = 0; }
}

__global__ void count_kernel(const int* __restrict__ dst, int E, int N,
                             int* __restrict__ deg) {
    int e = blockIdx.x * blockDim.x + threadIdx.x;
    if (e >= E + N) return;
    int d = (e < E) ? dst[e] : e - E;
    atomicAdd(&deg[d], 1);
}

// single-block exclusive scan of deg[0:N] -> off[0:N+1]
__global__ void scan_kernel(const int* __restrict__ deg,
                            int* __restrict__ off, int N) {
    __shared__ int part[SCAN_T];
    int t = threadIdx.x;
    int chunk = (N + SCAN_T - 1) / SCAN_T;
    int lo = t * chunk, hi = min(lo + chunk, N);
    int s = 0;
    for (int i = lo; i < hi; ++i) s += deg[i];
    part[t] = s;
    __syncthreads();
    for (int d = 1; d < SCAN_T; d <<= 1) {
        int v = (t >= d) ? part[t - d] : 0;
        __syncthreads();
        part[t] += v;
        __syncthreads();
    }
    int run = (t > 0) ? part[t - 1] : 0;   // exclusive base
    for (int i = lo; i < hi; ++i) { off[i] = run; run += deg[i]; }
    if (t == SCAN_T - 1) off[N] = part[SCAN_T - 1];
}

__global__ void scatter_kernel(const int* __restrict__ src,
                               const int* __restrict__ dst, int E, int N,
                               const int* __restrict__ off,
                               int* __restrict__ cursor,
                               int* __restrict__ csr_src) {
    int e = blockIdx.x * blockDim.x + threadIdx.x;
    if (e >= E + N) return;
    int s, d;
    if (e < E) { s = src[e]; d = dst[e]; } else { s = d = e - E; }
    int p = atomicAdd(&cursor[d], 1);
    csr_src[off[d] + p] = s;
}

// ---------------------------------------------------------------------------
// Per-node softmax: wave per node. Lanes stride over incoming edges,
// butterfly-reduce max & sum per head; write ex (CSR order) and 1/denom.
__global__ void node_softmax_kernel(const int* __restrict__ off,
                                    const int* __restrict__ csr_src,
                                    const float4* __restrict__ asrc4,
                                    const float4* __restrict__ adst4,
                                    float4* __restrict__ exw,
                                    float4* __restrict__ invden, int N) {
    int node = (blockIdx.x * blockDim.x + threadIdx.x) >> 6;
    int lane = threadIdx.x & 63;
    if (node >= N) return;
    int o0 = off[node], o1 = off[node + 1];
    int deg = o1 - o0;
    float4 ad = adst4[node];

    float4 evreg[4];
    float4 mx = make_float4(-INFINITY, -INFINITY, -INFINITY, -INFINITY);
    int cnt = 0;
    for (int i = lane; i < deg; i += 64) {
        int s = csr_src[o0 + i];
        float4 as = asrc4[s];
        float4 ev;
        ev.x = lrelu(as.x + ad.x);
        ev.y = lrelu(as.y + ad.y);
        ev.z = lrelu(as.z + ad.z);
        ev.w = lrelu(as.w + ad.w);
        if (cnt < 4) evreg[cnt] = ev;
        ++cnt;
        mx.x = fmaxf(mx.x, ev.x);
        mx.y = fmaxf(mx.y, ev.y);
        mx.z = fmaxf(mx.z, ev.z);
        mx.w = fmaxf(mx.w, ev.w);
    }
#pragma unroll
    for (int m = 32; m; m >>= 1) {
        mx.x = fmaxf(mx.x, __shfl_xor(mx.x, m));
        mx.y = fmaxf(mx.y, __shfl_xor(mx.y, m));
        mx.z = fmaxf(mx.z, __shfl_xor(mx.z, m));
        mx.w = fmaxf(mx.w, __shfl_xor(mx.w, m));
    }
    float4 sum = make_float4(0.f, 0.f, 0.f, 0.f);
    int j = 0;
    for (int i = lane; i < deg; i += 64, ++j) {
        float4 ev;
        if (j < 4) {
            ev = evreg[j];
        } else {                       // degree > 256: recompute (rare)
            int s = csr_src[o0 + i];
            float4 as = asrc4[s];
            ev.x = lrelu(as.x + ad.x);
            ev.y = lrelu(as.y + ad.y);
            ev.z = lrelu(as.z + ad.z);
            ev.w = lrelu(as.w + ad.w);
        }
        float4 ex;
        ex.x = expf(ev.x - mx.x);
        ex.y = expf(ev.y - mx.y);
        ex.z = expf(ev.z - mx.z);
        ex.w = expf(ev.w - mx.w);
        exw[o0 + i] = ex;
        sum.x += ex.x; sum.y += ex.y; sum.z += ex.z; sum.w += ex.w;
    }
#pragma unroll
    for (int m = 32; m; m >>= 1) {
        sum.x += __shfl_xor(sum.x, m);
        sum.y += __shfl_xor(sum.y, m);
        sum.z += __shfl_xor(sum.z, m);
        sum.w += __shfl_xor(sum.w, m);
    }
    if (lane == 0) {
        float4 iv;
        iv.x = 1.f / sum.x; iv.y = 1.f / sum.y;
        iv.z = 1.f / sum.z; iv.w = 1.f / sum.w;
        invden[node] = iv;
    }
}

// ---------------------------------------------------------------------------
// Per-node aggregation: wave per node, lane = channel. No atomics.
// out[d,c] = elu( (1/H) * sum_e sum_h hbuf[s,h,c]*w[e,h] + b[c] ) + residual
__global__ void node_agg_kernel(const int* __restrict__ off,
                                const int* __restrict__ csr_src,
                                const float4* __restrict__ exw,
                                const float4* __restrict__ invden,
                                const float* __restrict__ hbuf,
                                const float* __restrict__ b,
                                const float* __restrict__ residual,
                                float* __restrict__ out, int N) {
    int node = (blockIdx.x * blockDim.x + threadIdx.x) >> 6;
    int c = threadIdx.x & 63;
    if (node >= N) return;
    int o0 = off[node], o1 = off[node + 1];
    float4 iv = invden[node];
    float acc = 0.f;
    int i = o0;
    for (; i + 1 < o1; i += 2) {
        int s0 = csr_src[i], s1 = csr_src[i + 1];
        float4 e0 = exw[i], e1 = exw[i + 1];
        const float* h0 = hbuf + (size_t)s0 * HC + c;
        const float* h1 = hbuf + (size_t)s1 * HC + c;
        acc += h0[0]      * (e0.x * iv.x) + h0[CH]     * (e0.y * iv.y)
             + h0[2 * CH] * (e0.z * iv.z) + h0[3 * CH] * (e0.w * iv.w);
        acc += h1[0]      * (e1.x * iv.x) + h1[CH]     * (e1.y * iv.y)
             + h1[2 * CH] * (e1.z * iv.z) + h1[3 * CH] * (e1.w * iv.w);
    }
    if (i < o1) {
        int s0 = csr_src[i];
        float4 e0 = exw[i];
        const float* h0 = hbuf + (size_t)s0 * HC + c;
        acc += h0[0]      * (e0.x * iv.x) + h0[CH]     * (e0.y * iv.y)
             + h0[2 * CH] * (e0.z * iv.z) + h0[3 * CH] * (e0.w * iv.w);
    }
    float v = acc * (1.0f / HEADS) + b[c];
    v = v > 0.f ? v : expm1f(v);
    if (residual) v += residual[(size_t)node * CH + c];
    out[(size_t)node * CH + c] = v;
}

// ---------------------------------------------------------------------------
__global__ void final_kernel(const float* __restrict__ h3,
                             const float* __restrict__ lin_w,
                             const float* __restrict__ lin_b,
                             float* __restrict__ out, int N) {
    long long gid = (long long)blockIdx.x * blockDim.x + threadIdx.x;
    if (gid >= (long long)N * 64) return;
    int n = (int)(gid >> 6);
    int lane = (int)(gid & 63);
    float v = h3[(size_t)n * CH + lane] * lin_w[lane];
    for (int off = 32; off; off >>= 1) v += __shfl_down(v, off);
    if (lane == 0) out[n] = v + lin_b[0];
}

// ---------------------------------------------------------------------------
extern "C" void kernel_launch(void* const* d_in, const int* in_sizes, int n_in,
                              void* d_out, int out_size, void* d_ws, size_t ws_size,
                              hipStream_t stream) {
    const float* x      = (const float*)d_in[0];
    const int*   ei     = (const int*)  d_in[1];
    const float* W1     = (const float*)d_in[2];
    const float* a1s    = (const float*)d_in[3];
    const float* a1d    = (const float*)d_in[4];
    const float* b1     = (const float*)d_in[5];
    const float* W2     = (const float*)d_in[6];
    const float* a2s    = (const float*)d_in[7];
    const float* a2d    = (const float*)d_in[8];
    const float* b2     = (const float*)d_in[9];
    const float* W3     = (const float*)d_in[10];
    const float* a3s    = (const float*)d_in[11];
    const float* a3d    = (const float*)d_in[12];
    const float* b3     = (const float*)d_in[13];
    const float* lin_w  = (const float*)d_in[14];
    const float* lin_b  = (const float*)d_in[15];

    const int N = in_sizes[0] / 3;
    const int E = in_sizes[1] / 2;
    const int Et = E + N;
    const int* src = ei;
    const int* dst = ei + E;

    float* ws    = (float*)d_ws;
    float* hbuf  = ws;                               // N*256
    float* asrc  = hbuf   + (size_t)N * HC;          // N*4
    float* adst  = asrc   + (size_t)N * HEADS;       // N*4
    float* invden= adst   + (size_t)N * HEADS;       // N*4
    float* bufA  = invden + (size_t)N * HEADS;       // N*64 (h1)
    float* bufB  = bufA   + (size_t)N * CH;          // N*64 (h2)
    float* bufC  = bufB   + (size_t)N * CH;          // N*64 (h3)
    float* exw   = bufC   + (size_t)N * CH;          // Et*4
    int*   deg    = (int*)(exw + (size_t)Et * HEADS); // N
    int*   cursor = deg    + N;                       // N
    int*   off    = cursor + N;                       // N+1
    int*   csr_src= off    + N + 1;                   // Et

    const int B = 256;

    // ---- CSR build (once; shared by all 3 layers) ----
    zero_int2<<<(N + B - 1) / B, B, 0, stream>>>(deg, cursor, N);
    count_kernel<<<(Et + B - 1) / B, B, 0, stream>>>(dst, E, N, deg);
    scan_kernel<<<1, SCAN_T, 0, stream>>>(deg, off, N);
    scatter_kernel<<<(Et + B - 1) / B, B, 0, stream>>>(src, dst, E, N, off,
                                                       cursor, csr_src);

    auto run_layer = [&](const float* inp, int K, const float* W,
                         const float* as, const float* ad, const float* bb,
                         const float* residual, float* outbuf) {
        feat_kernel<<<(N + NPB - 1) / NPB, B, 0, stream>>>(
            inp, K, W, as, ad, hbuf, asrc, adst, N);
        int nwave_blocks = (N * 64 + B - 1) / B;   // wave per node
        node_softmax_kernel<<<nwave_blocks, B, 0, stream>>>(
            off, csr_src, (const float4*)asrc, (const float4*)adst,
            (float4*)exw, (float4*)invden, N);
        node_agg_kernel<<<nwave_blocks, B, 0, stream>>>(
            off, csr_src, (const float4*)exw, (const float4*)invden,
            hbuf, bb, residual, outbuf, N);
    };

    run_layer(x,    3,  W1, a1s, a1d, b1, nullptr, bufA);  // h1
    run_layer(bufA, 64, W2, a2s, a2d, b2, bufA,    bufB);  // h2 = elu(.)+h1
    run_layer(bufB, 64, W3, a3s, a3d, b3, bufB,    bufC);  // h3 = elu(.)+h2

    long long fin_threads = (long long)N * 64;
    final_kernel<<<(int)((fin_threads + B - 1) / B), B, 0, stream>>>(
        bufC, lin_w, lin_b, (float*)d_out, N);
}

// Round 4
// 761.451 us; speedup vs baseline: 2.3343x; 1.0886x over previous
//
#include <hip/hip_runtime.h>
#include <math.h>

#define HEADS 4
#define CH 64
#define HC 256   // HEADS*CH
#define NPB 8    // nodes per block in feat_kernel
#define SCAN_T 1024

__device__ __forceinline__ float lrelu(float v) { return v > 0.f ? v : 0.2f * v; }

__device__ __forceinline__ float4 wave_max4(float4 v) {
#pragma unroll
    for (int m = 32; m; m >>= 1) {
        v.x = fmaxf(v.x, __shfl_xor(v.x, m));
        v.y = fmaxf(v.y, __shfl_xor(v.y, m));
        v.z = fmaxf(v.z, __shfl_xor(v.z, m));
        v.w = fmaxf(v.w, __shfl_xor(v.w, m));
    }
    return v;
}

__device__ __forceinline__ float4 wave_sum4(float4 v) {
#pragma unroll
    for (int m = 32; m; m >>= 1) {
        v.x += __shfl_xor(v.x, m);
        v.y += __shfl_xor(v.y, m);
        v.z += __shfl_xor(v.z, m);
        v.w += __shfl_xor(v.w, m);
    }
    return v;
}

// ---------------------------------------------------------------------------
// Per-node transform: hbufT[n, c*4+h] = (in[n,:] @ W)[h*64+c]  (channel-major
// so the agg kernel can do one float4 load per edge), plus per-head logits.
__global__ void feat_kernel(const float* __restrict__ in, int K,
                            const float* __restrict__ W,
                            const float* __restrict__ a_src,
                            const float* __restrict__ a_dst,
                            float* __restrict__ hbufT,
                            float* __restrict__ asrc,
                            float* __restrict__ adst, int N) {
    __shared__ float xrow[NPB][64];
    int t = threadIdx.x;
    int base = blockIdx.x * NPB;
    for (int i = t; i < NPB * K; i += 256) {
        int nb = i / K, k = i - nb * K;
        int n = base + nb;
        if (n < N) xrow[nb][k] = in[(size_t)n * K + k];
    }
    __syncthreads();
    float acc[NPB];
#pragma unroll
    for (int nb = 0; nb < NPB; ++nb) acc[nb] = 0.f;
    for (int k = 0; k < K; ++k) {
        float w = W[k * HC + t];
#pragma unroll
        for (int nb = 0; nb < NPB; ++nb) acc[nb] += xrow[nb][k] * w;
    }
    int head = t >> 6, lane = t & 63;
    float aw_s = a_src[t], aw_d = a_dst[t];
    int tidx = lane * HEADS + head;   // transposed store index
#pragma unroll
    for (int nb = 0; nb < NPB; ++nb) {
        int n = base + nb;
        if (n >= N) break;
        hbufT[(size_t)n * HC + tidx] = acc[nb];
        float vs = acc[nb] * aw_s, vd = acc[nb] * aw_d;
        for (int off = 32; off; off >>= 1) {
            vs += __shfl_down(vs, off);
            vd += __shfl_down(vd, off);
        }
        if (lane == 0) {
            asrc[n * HEADS + head] = vs;
            adst[n * HEADS + head] = vd;
        }
    }
}

// ---------------------------------------------------------------------------
// CSR build (once per call; graph shared by all 3 layers)
__global__ void zero_int2(int* __restrict__ a, int* __restrict__ b, int n) {
    int i = blockIdx.x * blockDim.x + threadIdx.x;
    if (i < n) { a[i] = 0; b[i] = 0; }
}

__global__ void count_kernel(const int* __restrict__ dst, int E, int N,
                             int* __restrict__ deg) {
    int e = blockIdx.x * blockDim.x + threadIdx.x;
    if (e >= E + N) return;
    int d = (e < E) ? dst[e] : e - E;
    atomicAdd(&deg[d], 1);
}

__global__ void scan_kernel(const int* __restrict__ deg,
                            int* __restrict__ off, int N) {
    __shared__ int part[SCAN_T];
    int t = threadIdx.x;
    int chunk = (N + SCAN_T - 1) / SCAN_T;
    int lo = t * chunk, hi = min(lo + chunk, N);
    int s = 0;
    for (int i = lo; i < hi; ++i) s += deg[i];
    part[t] = s;
    __syncthreads();
    for (int d = 1; d < SCAN_T; d <<= 1) {
        int v = (t >= d) ? part[t - d] : 0;
        __syncthreads();
        part[t] += v;
        __syncthreads();
    }
    int run = (t > 0) ? part[t - 1] : 0;
    for (int i = lo; i < hi; ++i) { off[i] = run; run += deg[i]; }
    if (t == SCAN_T - 1) off[N] = part[SCAN_T - 1];
}

__global__ void scatter_kernel(const int* __restrict__ src,
                               const int* __restrict__ dst, int E, int N,
                               const int* __restrict__ off,
                               int* __restrict__ cursor,
                               int* __restrict__ csr_src) {
    int e = blockIdx.x * blockDim.x + threadIdx.x;
    if (e >= E + N) return;
    int s, d;
    if (e < E) { s = src[e]; d = dst[e]; } else { s = d = e - E; }
    int p = atomicAdd(&cursor[d], 1);
    csr_src[off[d] + p] = s;
}

// ---------------------------------------------------------------------------
// Fused softmax + aggregation: one wave per dst node.
// Phase 1 (lanes = edges): online-softmax over <=64-edge chunks.
// Phase 2 (lanes = channels): broadcast per-edge weights via __shfl, gather
// hbufT rows (one float4 = 4 heads per lane), per-head register accumulators.
// Epilogue: head-mean + bias + ELU + residual; optional fused final linear.
__global__ void node_fused_kernel(const int* __restrict__ off,
                                  const int* __restrict__ csr_src,
                                  const float4* __restrict__ asrc4,
                                  const float4* __restrict__ adst4,
                                  const float4* __restrict__ hbufT4,
                                  const float* __restrict__ b,
                                  const float* __restrict__ residual,
                                  const float* __restrict__ lin_w,
                                  const float* __restrict__ lin_b,
                                  float* __restrict__ out, int N) {
    int node = (blockIdx.x * blockDim.x + threadIdx.x) >> 6;
    int lane = threadIdx.x & 63;
    if (node >= N) return;
    int o0 = off[node], o1 = off[node + 1];
    int deg = o1 - o0;
    float4 ad = adst4[node];

    float m0 = -INFINITY, m1 = -INFINITY, m2 = -INFINITY, m3 = -INFINITY;
    float l0 = 0.f, l1 = 0.f, l2 = 0.f, l3 = 0.f;
    float a0 = 0.f, a1 = 0.f, a2 = 0.f, a3 = 0.f;

    for (int base = 0; base < deg; base += 64) {
        int i = base + lane;
        int s = 0;
        float4 as = make_float4(-INFINITY, -INFINITY, -INFINITY, -INFINITY);
        if (i < deg) { s = csr_src[o0 + i]; as = asrc4[s]; }
        float4 ev;
        ev.x = lrelu(as.x + ad.x);
        ev.y = lrelu(as.y + ad.y);
        ev.z = lrelu(as.z + ad.z);
        ev.w = lrelu(as.w + ad.w);
        float4 mc = wave_max4(ev);
        float n0 = fmaxf(m0, mc.x), n1 = fmaxf(m1, mc.y);
        float n2 = fmaxf(m2, mc.z), n3 = fmaxf(m3, mc.w);
        float r0 = expf(m0 - n0), r1 = expf(m1 - n1);
        float r2 = expf(m2 - n2), r3 = expf(m3 - n3);
        float4 ex;
        ex.x = expf(ev.x - n0);   // inactive lanes: exp(-inf) = 0
        ex.y = expf(ev.y - n1);
        ex.z = expf(ev.z - n2);
        ex.w = expf(ev.w - n3);
        float4 ls = wave_sum4(ex);
        l0 = l0 * r0 + ls.x; l1 = l1 * r1 + ls.y;
        l2 = l2 * r2 + ls.z; l3 = l3 * r3 + ls.w;
        a0 *= r0; a1 *= r1; a2 *= r2; a3 *= r3;
        m0 = n0; m1 = n1; m2 = n2; m3 = n3;

        int cnt = min(64, deg - base);
#pragma unroll 2
        for (int e = 0; e < cnt; ++e) {
            int se = __shfl(s, e);
            float w0 = __shfl(ex.x, e);
            float w1 = __shfl(ex.y, e);
            float w2 = __shfl(ex.z, e);
            float w3 = __shfl(ex.w, e);
            float4 h = hbufT4[(size_t)se * CH + lane];
            a0 += h.x * w0; a1 += h.y * w1;
            a2 += h.z * w2; a3 += h.w * w3;
        }
    }

    float v = (a0 / l0 + a1 / l1 + a2 / l2 + a3 / l3) * 0.25f + b[lane];
    v = v > 0.f ? v : expm1f(v);
    if (residual) v += residual[(size_t)node * CH + lane];
    if (!lin_w) {
        out[(size_t)node * CH + lane] = v;
    } else {
        float t = v * lin_w[lane];
#pragma unroll
        for (int m = 32; m; m >>= 1) t += __shfl_xor(t, m);
        if (lane == 0) out[node] = t + lin_b[0];
    }
}

// ---------------------------------------------------------------------------
extern "C" void kernel_launch(void* const* d_in, const int* in_sizes, int n_in,
                              void* d_out, int out_size, void* d_ws, size_t ws_size,
                              hipStream_t stream) {
    const float* x      = (const float*)d_in[0];
    const int*   ei     = (const int*)  d_in[1];
    const float* W1     = (const float*)d_in[2];
    const float* a1s    = (const float*)d_in[3];
    const float* a1d    = (const float*)d_in[4];
    const float* b1     = (const float*)d_in[5];
    const float* W2     = (const float*)d_in[6];
    const float* a2s    = (const float*)d_in[7];
    const float* a2d    = (const float*)d_in[8];
    const float* b2     = (const float*)d_in[9];
    const float* W3     = (const float*)d_in[10];
    const float* a3s    = (const float*)d_in[11];
    const float* a3d    = (const float*)d_in[12];
    const float* b3     = (const float*)d_in[13];
    const float* lin_w  = (const float*)d_in[14];
    const float* lin_b  = (const float*)d_in[15];

    const int N = in_sizes[0] / 3;
    const int E = in_sizes[1] / 2;
    const int Et = E + N;
    const int* src = ei;
    const int* dst = ei + E;

    float* ws    = (float*)d_ws;
    float* hbufT = ws;                               // N*256 (channel-major)
    float* asrc  = hbufT  + (size_t)N * HC;          // N*4
    float* adst  = asrc   + (size_t)N * HEADS;       // N*4
    float* bufA  = adst   + (size_t)N * HEADS;       // N*64 (h1)
    float* bufB  = bufA   + (size_t)N * CH;          // N*64 (h2)
    int*   deg    = (int*)(bufB + (size_t)N * CH);   // N
    int*   cursor = deg    + N;                      // N
    int*   off    = cursor + N;                      // N+1
    int*   csr_src= off    + N + 1;                  // Et

    const int B = 256;

    // ---- CSR build (once; shared by all 3 layers) ----
    zero_int2<<<(N + B - 1) / B, B, 0, stream>>>(deg, cursor, N);
    count_kernel<<<(Et + B - 1) / B, B, 0, stream>>>(dst, E, N, deg);
    scan_kernel<<<1, SCAN_T, 0, stream>>>(deg, off, N);
    scatter_kernel<<<(Et + B - 1) / B, B, 0, stream>>>(src, dst, E, N, off,
                                                       cursor, csr_src);

    int nwave_blocks = (N * 64 + B - 1) / B;   // wave per node

    auto run_layer = [&](const float* inp, int K, const float* W,
                         const float* as, const float* ad, const float* bb,
                         const float* residual, const float* lw,
                         const float* lb, float* outbuf) {
        feat_kernel<<<(N + NPB - 1) / NPB, B, 0, stream>>>(
            inp, K, W, as, ad, hbufT, asrc, adst, N);
        node_fused_kernel<<<nwave_blocks, B, 0, stream>>>(
            off, csr_src, (const float4*)asrc, (const float4*)adst,
            (const float4*)hbufT, bb, residual, lw, lb, outbuf, N);
    };

    run_layer(x,    3,  W1, a1s, a1d, b1, nullptr, nullptr, nullptr, bufA);
    run_layer(bufA, 64, W2, a2s, a2d, b2, bufA,    nullptr, nullptr, bufB);
    // layer 3: fused final linear writes d_out[N] directly
    run_layer(bufB, 64, W3, a3s, a3d, b3, bufB,    lin_w,   lin_b, (float*)d_out);
}

// Round 5
// 652.845 us; speedup vs baseline: 2.7226x; 1.1664x over previous
//
#include <hip/hip_runtime.h>
#include <math.h>

#define HEADS 4
#define CH 64
#define HC 256   // HEADS*CH
#define NPB 8    // nodes per block in feat_kernel
#define SCAN_T 1024

__device__ __forceinline__ float lrelu(float v) { return v > 0.f ? v : 0.2f * v; }

// fp32 -> bf16 bits, round-to-nearest-even
__device__ __forceinline__ unsigned int f2bf(float f) {
    unsigned int u = __float_as_uint(f);
    u += 0x7fffu + ((u >> 16) & 1u);
    return u >> 16;
}

__device__ __forceinline__ float4 wave_max4(float4 v) {
#pragma unroll
    for (int m = 32; m; m >>= 1) {
        v.x = fmaxf(v.x, __shfl_xor(v.x, m));
        v.y = fmaxf(v.y, __shfl_xor(v.y, m));
        v.z = fmaxf(v.z, __shfl_xor(v.z, m));
        v.w = fmaxf(v.w, __shfl_xor(v.w, m));
    }
    return v;
}

__device__ __forceinline__ float4 wave_sum4(float4 v) {
#pragma unroll
    for (int m = 32; m; m >>= 1) {
        v.x += __shfl_xor(v.x, m);
        v.y += __shfl_xor(v.y, m);
        v.z += __shfl_xor(v.z, m);
        v.w += __shfl_xor(v.w, m);
    }
    return v;
}

// ---------------------------------------------------------------------------
// Per-node transform. h = in[n,:] @ W  (fp32); logits from fp32 h; message
// buffer stored as packed bf16: hbufB[n*64 + c] = uint2{bf(h0),bf(h1) |
// bf(h2),bf(h3)} (4 heads of channel c). Stores staged through LDS so the
// global write is one contiguous 512B row per node.
__global__ void feat_kernel(const float* __restrict__ in, int K,
                            const float* __restrict__ W,
                            const float* __restrict__ a_src,
                            const float* __restrict__ a_dst,
                            uint2* __restrict__ hbufB,
                            float* __restrict__ asrc,
                            float* __restrict__ adst, int N) {
    __shared__ float xrow[NPB][64];
    __shared__ float trow[HC];
    int t = threadIdx.x;
    int base = blockIdx.x * NPB;
    for (int i = t; i < NPB * K; i += 256) {
        int nb = i / K, k = i - nb * K;
        int n = base + nb;
        if (n < N) xrow[nb][k] = in[(size_t)n * K + k];
    }
    __syncthreads();
    float acc[NPB];
#pragma unroll
    for (int nb = 0; nb < NPB; ++nb) acc[nb] = 0.f;
    for (int k = 0; k < K; ++k) {
        float w = W[k * HC + t];
#pragma unroll
        for (int nb = 0; nb < NPB; ++nb) acc[nb] += xrow[nb][k] * w;
    }
    int head = t >> 6, lane = t & 63;
    float aw_s = a_src[t], aw_d = a_dst[t];
#pragma unroll
    for (int nb = 0; nb < NPB; ++nb) {
        int n = base + nb;           // block-uniform
        if (n >= N) break;
        float vs = acc[nb] * aw_s, vd = acc[nb] * aw_d;
        for (int off = 32; off; off >>= 1) {
            vs += __shfl_down(vs, off);
            vd += __shfl_down(vd, off);
        }
        if (lane == 0) {
            asrc[n * HEADS + head] = vs;
            adst[n * HEADS + head] = vd;
        }
        trow[t] = acc[nb];
        __syncthreads();
        if (t < 64) {
            uint2 p;
            p.x = f2bf(trow[t])       | (f2bf(trow[64 + t])  << 16);
            p.y = f2bf(trow[128 + t]) | (f2bf(trow[192 + t]) << 16);
            hbufB[(size_t)n * CH + t] = p;
        }
        __syncthreads();
    }
}

// ---------------------------------------------------------------------------
// CSR build (once per call; graph shared by all 3 layers)
__global__ void zero_int2(int* __restrict__ a, int* __restrict__ b, int n) {
    int i = blockIdx.x * blockDim.x + threadIdx.x;
    if (i < n) { a[i] = 0; b[i] = 0; }
}

__global__ void count_kernel(const int* __restrict__ dst, int E, int N,
                             int* __restrict__ deg) {
    int e = blockIdx.x * blockDim.x + threadIdx.x;
    if (e >= E + N) return;
    int d = (e < E) ? dst[e] : e - E;
    atomicAdd(&deg[d], 1);
}

__global__ void scan_kernel(const int* __restrict__ deg,
                            int* __restrict__ off, int N) {
    __shared__ int part[SCAN_T];
    int t = threadIdx.x;
    int chunk = (N + SCAN_T - 1) / SCAN_T;
    int lo = t * chunk, hi = min(lo + chunk, N);
    int s = 0;
    for (int i = lo; i < hi; ++i) s += deg[i];
    part[t] = s;
    __syncthreads();
    for (int d = 1; d < SCAN_T; d <<= 1) {
        int v = (t >= d) ? part[t - d] : 0;
        __syncthreads();
        part[t] += v;
        __syncthreads();
    }
    int run = (t > 0) ? part[t - 1] : 0;
    for (int i = lo; i < hi; ++i) { off[i] = run; run += deg[i]; }
    if (t == SCAN_T - 1) off[N] = part[SCAN_T - 1];
}

__global__ void scatter_kernel(const int* __restrict__ src,
                               const int* __restrict__ dst, int E, int N,
                               const int* __restrict__ off,
                               int* __restrict__ cursor,
                               int* __restrict__ csr_src) {
    int e = blockIdx.x * blockDim.x + threadIdx.x;
    if (e >= E + N) return;
    int s, d;
    if (e < E) { s = src[e]; d = dst[e]; } else { s = d = e - E; }
    int p = atomicAdd(&cursor[d], 1);
    csr_src[off[d] + p] = s;
}

// ---------------------------------------------------------------------------
// Fused softmax + aggregation: one wave per dst node.
// Phase 1 (lanes = edges): online-softmax, fp32 logits.
// Phase 2 (lanes = channels): shfl-broadcast weights; gather packed-bf16
// rows (uint2 = 4 heads / 8B per lane), per-head fp32 accumulators.
__global__ void node_fused_kernel(const int* __restrict__ off,
                                  const int* __restrict__ csr_src,
                                  const float4* __restrict__ asrc4,
                                  const float4* __restrict__ adst4,
                                  const uint2* __restrict__ hbufB,
                                  const float* __restrict__ b,
                                  const float* __restrict__ residual,
                                  const float* __restrict__ lin_w,
                                  const float* __restrict__ lin_b,
                                  float* __restrict__ out, int N) {
    int node = (blockIdx.x * blockDim.x + threadIdx.x) >> 6;
    int lane = threadIdx.x & 63;
    if (node >= N) return;
    int o0 = off[node], o1 = off[node + 1];
    int deg = o1 - o0;
    float4 ad = adst4[node];

    float m0 = -INFINITY, m1 = -INFINITY, m2 = -INFINITY, m3 = -INFINITY;
    float l0 = 0.f, l1 = 0.f, l2 = 0.f, l3 = 0.f;
    float a0 = 0.f, a1 = 0.f, a2 = 0.f, a3 = 0.f;

    for (int base = 0; base < deg; base += 64) {
        int i = base + lane;
        int s = 0;
        float4 as = make_float4(-INFINITY, -INFINITY, -INFINITY, -INFINITY);
        if (i < deg) { s = csr_src[o0 + i]; as = asrc4[s]; }
        float4 ev;
        ev.x = lrelu(as.x + ad.x);
        ev.y = lrelu(as.y + ad.y);
        ev.z = lrelu(as.z + ad.z);
        ev.w = lrelu(as.w + ad.w);
        float4 mc = wave_max4(ev);
        float n0 = fmaxf(m0, mc.x), n1 = fmaxf(m1, mc.y);
        float n2 = fmaxf(m2, mc.z), n3 = fmaxf(m3, mc.w);
        float r0 = expf(m0 - n0), r1 = expf(m1 - n1);
        float r2 = expf(m2 - n2), r3 = expf(m3 - n3);
        float4 ex;
        ex.x = expf(ev.x - n0);   // inactive lanes: exp(-inf) = 0
        ex.y = expf(ev.y - n1);
        ex.z = expf(ev.z - n2);
        ex.w = expf(ev.w - n3);
        float4 ls = wave_sum4(ex);
        l0 = l0 * r0 + ls.x; l1 = l1 * r1 + ls.y;
        l2 = l2 * r2 + ls.z; l3 = l3 * r3 + ls.w;
        a0 *= r0; a1 *= r1; a2 *= r2; a3 *= r3;
        m0 = n0; m1 = n1; m2 = n2; m3 = n3;

        int cnt = min(64, deg - base);
#pragma unroll 2
        for (int e = 0; e < cnt; ++e) {
            int se = __shfl(s, e);
            float w0 = __shfl(ex.x, e);
            float w1 = __shfl(ex.y, e);
            float w2 = __shfl(ex.z, e);
            float w3 = __shfl(ex.w, e);
            uint2 h = hbufB[(size_t)se * CH + lane];
            float h0 = __uint_as_float(h.x << 16);
            float h1 = __uint_as_float(h.x & 0xFFFF0000u);
            float h2 = __uint_as_float(h.y << 16);
            float h3 = __uint_as_float(h.y & 0xFFFF0000u);
            a0 += h0 * w0; a1 += h1 * w1;
            a2 += h2 * w2; a3 += h3 * w3;
        }
    }

    float v = (a0 / l0 + a1 / l1 + a2 / l2 + a3 / l3) * 0.25f + b[lane];
    v = v > 0.f ? v : expm1f(v);
    if (residual) v += residual[(size_t)node * CH + lane];
    if (!lin_w) {
        out[(size_t)node * CH + lane] = v;
    } else {
        float t = v * lin_w[lane];
#pragma unroll
        for (int m = 32; m; m >>= 1) t += __shfl_xor(t, m);
        if (lane == 0) out[node] = t + lin_b[0];
    }
}

// ---------------------------------------------------------------------------
extern "C" void kernel_launch(void* const* d_in, const int* in_sizes, int n_in,
                              void* d_out, int out_size, void* d_ws, size_t ws_size,
                              hipStream_t stream) {
    const float* x      = (const float*)d_in[0];
    const int*   ei     = (const int*)  d_in[1];
    const float* W1     = (const float*)d_in[2];
    const float* a1s    = (const float*)d_in[3];
    const float* a1d    = (const float*)d_in[4];
    const float* b1     = (const float*)d_in[5];
    const float* W2     = (const float*)d_in[6];
    const float* a2s    = (const float*)d_in[7];
    const float* a2d    = (const float*)d_in[8];
    const float* b2     = (const float*)d_in[9];
    const float* W3     = (const float*)d_in[10];
    const float* a3s    = (const float*)d_in[11];
    const float* a3d    = (const float*)d_in[12];
    const float* b3     = (const float*)d_in[13];
    const float* lin_w  = (const float*)d_in[14];
    const float* lin_b  = (const float*)d_in[15];

    const int N = in_sizes[0] / 3;
    const int E = in_sizes[1] / 2;
    const int Et = E + N;
    const int* src = ei;
    const int* dst = ei + E;

    float* ws    = (float*)d_ws;
    uint2* hbufB = (uint2*)ws;                       // N*64 uint2 (bf16 x4)
    float* asrc  = ws     + (size_t)N * 128;         // N*4
    float* adst  = asrc   + (size_t)N * HEADS;       // N*4
    float* bufA  = adst   + (size_t)N * HEADS;       // N*64 (h1)
    float* bufB  = bufA   + (size_t)N * CH;          // N*64 (h2)
    int*   deg    = (int*)(bufB + (size_t)N * CH);   // N
    int*   cursor = deg    + N;                      // N
    int*   off    = cursor + N;                      // N+1
    int*   csr_src= off    + N + 1;                  // Et

    const int B = 256;

    // ---- CSR build (once; shared by all 3 layers) ----
    zero_int2<<<(N + B - 1) / B, B, 0, stream>>>(deg, cursor, N);
    count_kernel<<<(Et + B - 1) / B, B, 0, stream>>>(dst, E, N, deg);
    scan_kernel<<<1, SCAN_T, 0, stream>>>(deg, off, N);
    scatter_kernel<<<(Et + B - 1) / B, B, 0, stream>>>(src, dst, E, N, off,
                                                       cursor, csr_src);

    int nwave_blocks = (N * 64 + B - 1) / B;   // wave per node

    auto run_layer = [&](const float* inp, int K, const float* W,
                         const float* as, const float* ad, const float* bb,
                         const float* residual, const float* lw,
                         const float* lb, float* outbuf) {
        feat_kernel<<<(N + NPB - 1) / NPB, B, 0, stream>>>(
            inp, K, W, as, ad, hbufB, asrc, adst, N);
        node_fused_kernel<<<nwave_blocks, B, 0, stream>>>(
            off, csr_src, (const float4*)asrc, (const float4*)adst,
            hbufB, bb, residual, lw, lb, outbuf, N);
    };

    run_layer(x,    3,  W1, a1s, a1d, b1, nullptr, nullptr, nullptr, bufA);
    run_layer(bufA, 64, W2, a2s, a2d, b2, bufA,    nullptr, nullptr, bufB);
    // layer 3: fused final linear writes d_out[N] directly
    run_layer(bufB, 64, W3, a3s, a3d, b3, bufB,    lin_w,   lin_b, (float*)d_out);
}

// Round 6
// 568.280 us; speedup vs baseline: 3.1278x; 1.1488x over previous
//
#include <hip/hip_runtime.h>
#include <math.h>

#define HEADS 4
#define CH 64
#define HC 256   // HEADS*CH
#define NPB 8    // nodes per block in feat_kernel

__device__ __forceinline__ float lrelu(float v) { return v > 0.f ? v : 0.2f * v; }

// fp32 -> bf16 bits, round-to-nearest-even
__device__ __forceinline__ unsigned int f2bf(float f) {
    unsigned int u = __float_as_uint(f);
    u += 0x7fffu + ((u >> 16) & 1u);
    return u >> 16;
}

__device__ __forceinline__ float4 wave_sum4(float4 v) {
#pragma unroll
    for (int m = 32; m; m >>= 1) {
        v.x += __shfl_xor(v.x, m);
        v.y += __shfl_xor(v.y, m);
        v.z += __shfl_xor(v.z, m);
        v.w += __shfl_xor(v.w, m);
    }
    return v;
}

// ---------------------------------------------------------------------------
// Per-node transform. h = in[n,:] @ W (fp32); logits from fp32 h; messages
// stored packed bf16 (uint2 = 4 heads of one channel). Two barriers/block.
__global__ void feat_kernel(const float* __restrict__ in, int K,
                            const float* __restrict__ W,
                            const float* __restrict__ a_src,
                            const float* __restrict__ a_dst,
                            uint2* __restrict__ hbufB,
                            float4* __restrict__ asrc4,
                            float4* __restrict__ adst4, int N) {
    __shared__ float xrow[NPB][64];
    __shared__ float trow[NPB][HC];        // 8 KB
    __shared__ float sred[NPB][2][HEADS];  // logits via LDS
    int t = threadIdx.x;
    int base = blockIdx.x * NPB;
    for (int i = t; i < NPB * K; i += 256) {
        int nb = i / K, k = i - nb * K;
        int n = base + nb;
        if (n < N) xrow[nb][k] = in[(size_t)n * K + k];
    }
    __syncthreads();
    float acc[NPB];
#pragma unroll
    for (int nb = 0; nb < NPB; ++nb) acc[nb] = 0.f;
    for (int k = 0; k < K; ++k) {
        float w = W[k * HC + t];
#pragma unroll
        for (int nb = 0; nb < NPB; ++nb) acc[nb] += xrow[nb][k] * w;
    }
    int head = t >> 6, lane = t & 63;
    float aw_s = a_src[t], aw_d = a_dst[t];
#pragma unroll
    for (int nb = 0; nb < NPB; ++nb) {
        trow[nb][t] = acc[nb];
        float vs = acc[nb] * aw_s, vd = acc[nb] * aw_d;
        for (int off = 32; off; off >>= 1) {
            vs += __shfl_down(vs, off);
            vd += __shfl_down(vd, off);
        }
        if (lane == 0) { sred[nb][0][head] = vs; sred[nb][1][head] = vd; }
    }
    __syncthreads();
    // packed bf16 stores: 512 (node,channel) pairs, coalesced uint2
    for (int i = t; i < NPB * CH; i += 256) {
        int nb = i >> 6, c = i & 63;
        int n = base + nb;
        if (n < N) {
            uint2 p;
            p.x = f2bf(trow[nb][c])        | (f2bf(trow[nb][64 + c])  << 16);
            p.y = f2bf(trow[nb][128 + c])  | (f2bf(trow[nb][192 + c]) << 16);
            hbufB[(size_t)n * CH + c] = p;
        }
    }
    if (t < NPB) {
        int n = base + t;
        if (n < N) {
            asrc4[n] = make_float4(sred[t][0][0], sred[t][0][1],
                                   sred[t][0][2], sred[t][0][3]);
            adst4[n] = make_float4(sred[t][1][0], sred[t][1][1],
                                   sred[t][1][2], sred[t][1][3]);
        }
    }
}

// ---------------------------------------------------------------------------
// CSR build (once per call; graph shared by all 3 layers)
__global__ void count_kernel(const int* __restrict__ dst, int E, int N,
                             int* __restrict__ deg) {
    int e = blockIdx.x * blockDim.x + threadIdx.x;
    if (e >= E + N) return;
    int d = (e < E) ? dst[e] : e - E;
    atomicAdd(&deg[d], 1);
}

// grid-wide exclusive scan, 3 kernels
__global__ void scan_blocks(const int* __restrict__ deg,
                            int* __restrict__ off,
                            int* __restrict__ bsum, int N) {
    __shared__ int sh[256];
    int t = threadIdx.x;
    int g = blockIdx.x * 256 + t;
    int v = (g < N) ? deg[g] : 0;
    sh[t] = v;
    __syncthreads();
    for (int d = 1; d < 256; d <<= 1) {
        int x = (t >= d) ? sh[t - d] : 0;
        __syncthreads();
        sh[t] += x;
        __syncthreads();
    }
    if (g < N) off[g] = sh[t] - v;                 // exclusive within block
    if (t == 255) bsum[blockIdx.x] = sh[255];
}

__global__ void scan_bsums(int* __restrict__ bsum, int G,
                           int* __restrict__ total_out) {
    __shared__ int sh[256];
    int t = threadIdx.x;
    int chunk = (G + 255) / 256;
    int lo = t * chunk, hi = min(lo + chunk, G);
    int s = 0;
    for (int i = lo; i < hi; ++i) s += bsum[i];
    sh[t] = s;
    __syncthreads();
    for (int d = 1; d < 256; d <<= 1) {
        int x = (t >= d) ? sh[t - d] : 0;
        __syncthreads();
        sh[t] += x;
        __syncthreads();
    }
    int run = (t > 0) ? sh[t - 1] : 0;
    for (int i = lo; i < hi; ++i) { int v = bsum[i]; bsum[i] = run; run += v; }
    if (t == 255) *total_out = sh[255];
}

__global__ void scan_add(int* __restrict__ off, const int* __restrict__ bsum,
                         int N) {
    int g = blockIdx.x * 256 + threadIdx.x;
    if (g < N) off[g] += bsum[blockIdx.x];
}

__global__ void scatter_kernel(const int* __restrict__ src,
                               const int* __restrict__ dst, int E, int N,
                               const int* __restrict__ off,
                               int* __restrict__ cursor,
                               int* __restrict__ csr_src) {
    int e = blockIdx.x * blockDim.x + threadIdx.x;
    if (e >= E + N) return;
    int s, d;
    if (e < E) { s = src[e]; d = dst[e]; } else { s = d = e - E; }
    int p = atomicAdd(&cursor[d], 1);
    csr_src[off[d] + p] = s;
}

// ---------------------------------------------------------------------------
// Fused softmax + aggregation: one wave per dst node.
// No max-subtraction (logits bounded; softmax shift-invariant): phase 1 is
// just ex = __expf(leaky_relu(as+ad)) and one butterfly sum. Phase 2
// broadcasts per-edge weights via __shfl (v_readlane) and gathers packed
// bf16 rows (uint2 = 4 heads / 8 B per lane), fp32 accumulators.
__global__ void node_fused_kernel(const int* __restrict__ off,
                                  const int* __restrict__ csr_src,
                                  const float4* __restrict__ asrc4,
                                  const float4* __restrict__ adst4,
                                  const uint2* __restrict__ hbufB,
                                  const float* __restrict__ b,
                                  const float* __restrict__ residual,
                                  const float* __restrict__ lin_w,
                                  const float* __restrict__ lin_b,
                                  float* __restrict__ out, int N) {
    int node = (blockIdx.x * blockDim.x + threadIdx.x) >> 6;
    int lane = threadIdx.x & 63;
    if (node >= N) return;
    int o0 = off[node], o1 = off[node + 1];
    int deg = o1 - o0;
    float4 ad = adst4[node];

    float l0 = 0.f, l1 = 0.f, l2 = 0.f, l3 = 0.f;
    float a0 = 0.f, a1 = 0.f, a2 = 0.f, a3 = 0.f;

    for (int base = 0; base < deg; base += 64) {
        int i = base + lane;
        int s = 0;
        float4 ev = make_float4(-INFINITY, -INFINITY, -INFINITY, -INFINITY);
        if (i < deg) {
            s = csr_src[o0 + i];
            float4 as = asrc4[s];
            ev.x = lrelu(as.x + ad.x);
            ev.y = lrelu(as.y + ad.y);
            ev.z = lrelu(as.z + ad.z);
            ev.w = lrelu(as.w + ad.w);
        }
        float4 ex;
        ex.x = __expf(ev.x);   // inactive lanes: exp(-inf) = 0
        ex.y = __expf(ev.y);
        ex.z = __expf(ev.z);
        ex.w = __expf(ev.w);
        float4 ls = wave_sum4(ex);
        l0 += ls.x; l1 += ls.y; l2 += ls.z; l3 += ls.w;

        int cnt = min(64, deg - base);
#pragma unroll 4
        for (int e = 0; e < cnt; ++e) {
            int se = __shfl(s, e);
            float w0 = __shfl(ex.x, e);
            float w1 = __shfl(ex.y, e);
            float w2 = __shfl(ex.z, e);
            float w3 = __shfl(ex.w, e);
            uint2 h = hbufB[(size_t)se * CH + lane];
            float h0 = __uint_as_float(h.x << 16);
            float h1 = __uint_as_float(h.x & 0xFFFF0000u);
            float h2 = __uint_as_float(h.y << 16);
            float h3 = __uint_as_float(h.y & 0xFFFF0000u);
            a0 += h0 * w0; a1 += h1 * w1;
            a2 += h2 * w2; a3 += h3 * w3;
        }
    }

    float v = (a0 / l0 + a1 / l1 + a2 / l2 + a3 / l3) * 0.25f + b[lane];
    v = v > 0.f ? v : expm1f(v);
    if (residual) v += residual[(size_t)node * CH + lane];
    if (!lin_w) {
        out[(size_t)node * CH + lane] = v;
    } else {
        float t = v * lin_w[lane];
#pragma unroll
        for (int m = 32; m; m >>= 1) t += __shfl_xor(t, m);
        if (lane == 0) out[node] = t + lin_b[0];
    }
}

// ---------------------------------------------------------------------------
extern "C" void kernel_launch(void* const* d_in, const int* in_sizes, int n_in,
                              void* d_out, int out_size, void* d_ws, size_t ws_size,
                              hipStream_t stream) {
    const float* x      = (const float*)d_in[0];
    const int*   ei     = (const int*)  d_in[1];
    const float* W1     = (const float*)d_in[2];
    const float* a1s    = (const float*)d_in[3];
    const float* a1d    = (const float*)d_in[4];
    const float* b1     = (const float*)d_in[5];
    const float* W2     = (const float*)d_in[6];
    const float* a2s    = (const float*)d_in[7];
    const float* a2d    = (const float*)d_in[8];
    const float* b2     = (const float*)d_in[9];
    const float* W3     = (const float*)d_in[10];
    const float* a3s    = (const float*)d_in[11];
    const float* a3d    = (const float*)d_in[12];
    const float* b3     = (const float*)d_in[13];
    const float* lin_w  = (const float*)d_in[14];
    const float* lin_b  = (const float*)d_in[15];

    const int N = in_sizes[0] / 3;
    const int E = in_sizes[1] / 2;
    const int Et = E + N;
    const int* src = ei;
    const int* dst = ei + E;

    float* ws    = (float*)d_ws;
    uint2* hbufB = (uint2*)ws;                       // N*64 uint2 (bf16 x4)
    float* asrc  = ws     + (size_t)N * 128;         // N*4
    float* adst  = asrc   + (size_t)N * HEADS;       // N*4
    float* bufA  = adst   + (size_t)N * HEADS;       // N*64 (h1)
    float* bufB  = bufA   + (size_t)N * CH;          // N*64 (h2)
    int*   deg    = (int*)(bufB + (size_t)N * CH);   // N
    int*   cursor = deg    + N;                      // N (adjacent: one memset)
    int*   off    = cursor + N;                      // N+1
    int*   bsum   = off    + N + 1;                  // <=256
    int*   csr_src= bsum   + 256;                    // Et

    const int B = 256;
    const int G = (N + 255) / 256;   // scan blocks (196 for N=50000)

    // ---- CSR build (once; shared by all 3 layers) ----
    hipMemsetAsync(deg, 0, (size_t)2 * N * sizeof(int), stream);  // deg+cursor
    count_kernel<<<(Et + B - 1) / B, B, 0, stream>>>(dst, E, N, deg);
    scan_blocks<<<G, B, 0, stream>>>(deg, off, bsum, N);
    scan_bsums<<<1, B, 0, stream>>>(bsum, G, off + N);
    scan_add<<<G, B, 0, stream>>>(off, bsum, N);
    scatter_kernel<<<(Et + B - 1) / B, B, 0, stream>>>(src, dst, E, N, off,
                                                       cursor, csr_src);

    int nwave_blocks = (N * 64 + B - 1) / B;   // wave per node

    auto run_layer = [&](const float* inp, int K, const float* W,
                         const float* as, const float* ad, const float* bb,
                         const float* residual, const float* lw,
                         const float* lb, float* outbuf) {
        feat_kernel<<<(N + NPB - 1) / NPB, B, 0, stream>>>(
            inp, K, W, as, ad, hbufB, (float4*)asrc, (float4*)adst, N);
        node_fused_kernel<<<nwave_blocks, B, 0, stream>>>(
            off, csr_src, (const float4*)asrc, (const float4*)adst,
            hbufB, bb, residual, lw, lb, outbuf, N);
    };

    run_layer(x,    3,  W1, a1s, a1d, b1, nullptr, nullptr, nullptr, bufA);
    run_layer(bufA, 64, W2, a2s, a2d, b2, bufA,    nullptr, nullptr, bufB);
    // layer 3: fused final linear writes d_out[N] directly
    run_layer(bufB, 64, W3, a3s, a3d, b3, bufB,    lin_w,   lin_b, (float*)d_out);
}

// Round 7
// 521.506 us; speedup vs baseline: 3.4083x; 1.0897x over previous
//
#include <hip/hip_runtime.h>
#include <math.h>

#define HEADS 4
#define CH 64
#define HC 256   // HEADS*CH
#define NPB 8    // nodes per block in feat_kernel

__device__ __forceinline__ float lrelu(float v) { return v > 0.f ? v : 0.2f * v; }

// fp32 -> bf16 bits, round-to-nearest-even
__device__ __forceinline__ unsigned int f2bf(float f) {
    unsigned int u = __float_as_uint(f);
    u += 0x7fffu + ((u >> 16) & 1u);
    return u >> 16;
}

__device__ __forceinline__ float4 wave_sum4(float4 v) {
#pragma unroll
    for (int m = 32; m; m >>= 1) {
        v.x += __shfl_xor(v.x, m);
        v.y += __shfl_xor(v.y, m);
        v.z += __shfl_xor(v.z, m);
        v.w += __shfl_xor(v.w, m);
    }
    return v;
}

// ---------------------------------------------------------------------------
// ws[k*4+h] = sum_c W[k, h*64+c] * a_s[h*64+c];  wd likewise. One small block.
__global__ void proj_kernel(const float* __restrict__ W,
                            const float* __restrict__ a_s,
                            const float* __restrict__ a_d,
                            int K, float* __restrict__ ws,
                            float* __restrict__ wd) {
    int t = threadIdx.x;
    int total = K * HEADS;
    for (int idx = t; idx < 2 * total; idx += blockDim.x) {
        int which = idx >= total;
        int i = which ? idx - total : idx;
        int k = i >> 2, h = i & 3;
        const float* av = (which ? a_d : a_s) + h * CH;
        const float* Wr = W + (size_t)k * HC + h * CH;
        float s = 0.f;
        for (int c = 0; c < CH; ++c) s += Wr[c] * av[c];
        (which ? wd : ws)[i] = s;
    }
}

// ---------------------------------------------------------------------------
// Layer-1 logits: asrc[n,h] = x[n,0:3] . ws[:,h]   (ws layout [k][h])
__global__ void logits1_kernel(const float* __restrict__ x,
                               const float* __restrict__ ws,
                               const float* __restrict__ wd,
                               float4* __restrict__ asrc4,
                               float4* __restrict__ adst4, int N) {
    int n = blockIdx.x * blockDim.x + threadIdx.x;
    if (n >= N) return;
    float x0 = x[3 * n], x1 = x[3 * n + 1], x2 = x[3 * n + 2];
    float4 s4, d4;
    s4.x = x0 * ws[0] + x1 * ws[4] + x2 * ws[8];
    s4.y = x0 * ws[1] + x1 * ws[5] + x2 * ws[9];
    s4.z = x0 * ws[2] + x1 * ws[6] + x2 * ws[10];
    s4.w = x0 * ws[3] + x1 * ws[7] + x2 * ws[11];
    d4.x = x0 * wd[0] + x1 * wd[4] + x2 * wd[8];
    d4.y = x0 * wd[1] + x1 * wd[5] + x2 * wd[9];
    d4.z = x0 * wd[2] + x1 * wd[6] + x2 * wd[10];
    d4.w = x0 * wd[3] + x1 * wd[7] + x2 * wd[11];
    asrc4[n] = s4;
    adst4[n] = d4;
}

// ---------------------------------------------------------------------------
// Layer-1 fused aggregation in INPUT space (x is 3-dim => 12 B gather/edge).
// Wave per node, lane per edge. z[h][k] = sum_e exp(ev_h) * x[s_e,k]; l[h].
// Output zl[node][4] float4s: {z[0..3]},{z[4..7]},{z[8..11]},{l[0..3]}.
__global__ void fused1_kernel(const int* __restrict__ off,
                              const int* __restrict__ csr_src,
                              const float* __restrict__ x,
                              const float4* __restrict__ asrc4,
                              const float4* __restrict__ adst4,
                              float4* __restrict__ zl, int N) {
    int node = (blockIdx.x * blockDim.x + threadIdx.x) >> 6;
    int lane = threadIdx.x & 63;
    if (node >= N) return;
    int o0 = off[node], o1 = off[node + 1];
    float4 ad = adst4[node];
    float z[12];
#pragma unroll
    for (int j = 0; j < 12; ++j) z[j] = 0.f;
    float l0 = 0.f, l1 = 0.f, l2 = 0.f, l3 = 0.f;

    for (int i = o0 + lane; i < o1; i += 64) {
        int s = csr_src[i];
        float4 as = asrc4[s];
        float e0 = __expf(lrelu(as.x + ad.x));
        float e1 = __expf(lrelu(as.y + ad.y));
        float e2 = __expf(lrelu(as.z + ad.z));
        float e3 = __expf(lrelu(as.w + ad.w));
        l0 += e0; l1 += e1; l2 += e2; l3 += e3;
        float x0 = x[3 * s], x1 = x[3 * s + 1], x2 = x[3 * s + 2];
        z[0] += e0 * x0; z[1]  += e0 * x1; z[2]  += e0 * x2;
        z[3] += e1 * x0; z[4]  += e1 * x1; z[5]  += e1 * x2;
        z[6] += e2 * x0; z[7]  += e2 * x1; z[8]  += e2 * x2;
        z[9] += e3 * x0; z[10] += e3 * x1; z[11] += e3 * x2;
    }
#pragma unroll
    for (int m = 32; m; m >>= 1) {
#pragma unroll
        for (int j = 0; j < 12; ++j) z[j] += __shfl_xor(z[j], m);
        l0 += __shfl_xor(l0, m); l1 += __shfl_xor(l1, m);
        l2 += __shfl_xor(l2, m); l3 += __shfl_xor(l3, m);
    }
    if (lane == 0) {
        zl[(size_t)node * 4 + 0] = make_float4(z[0], z[1], z[2], z[3]);
        zl[(size_t)node * 4 + 1] = make_float4(z[4], z[5], z[6], z[7]);
        zl[(size_t)node * 4 + 2] = make_float4(z[8], z[9], z[10], z[11]);
        zl[(size_t)node * 4 + 3] = make_float4(l0, l1, l2, l3);
    }
}

// ---------------------------------------------------------------------------
// Layer-1 epilogue: out[n,c] = elu( (1/4) sum_h (1/l_h) sum_k z[h,k]*W1[k,h*64+c] + b[c] )
__global__ void epi1_kernel(const float4* __restrict__ zl,
                            const float* __restrict__ W1,
                            const float* __restrict__ b1,
                            float* __restrict__ out, int N) {
    int node = (blockIdx.x * blockDim.x + threadIdx.x) >> 6;
    int c = threadIdx.x & 63;
    if (node >= N) return;
    float4 z0 = zl[(size_t)node * 4 + 0];
    float4 z1 = zl[(size_t)node * 4 + 1];
    float4 z2 = zl[(size_t)node * 4 + 2];
    float4 l4 = zl[(size_t)node * 4 + 3];
    float i0 = 0.25f / l4.x, i1 = 0.25f / l4.y;
    float i2 = 0.25f / l4.z, i3 = 0.25f / l4.w;
    // z order: [h0k0,h0k1,h0k2, h1k0,h1k1,h1k2, h2k0,h2k1,h2k2, h3k0,h3k1,h3k2]
    float acc =
        (z0.x * W1[0 * HC +   0 + c] + z0.y * W1[1 * HC +   0 + c] + z0.z * W1[2 * HC +   0 + c]) * i0 +
        (z0.w * W1[0 * HC +  64 + c] + z1.x * W1[1 * HC +  64 + c] + z1.y * W1[2 * HC +  64 + c]) * i1 +
        (z1.z * W1[0 * HC + 128 + c] + z1.w * W1[1 * HC + 128 + c] + z2.x * W1[2 * HC + 128 + c]) * i2 +
        (z2.y * W1[0 * HC + 192 + c] + z2.z * W1[1 * HC + 192 + c] + z2.w * W1[2 * HC + 192 + c]) * i3;
    float v = acc + b1[c];
    v = v > 0.f ? v : expm1f(v);
    out[(size_t)node * CH + c] = v;
}

// ---------------------------------------------------------------------------
// Per-node transform (layers 2/3, K=64). h = in @ W (fp32); logits from fp32;
// messages stored packed bf16 (uint2 = 4 heads of one channel).
__global__ void feat_kernel(const float* __restrict__ in, int K,
                            const float* __restrict__ W,
                            const float* __restrict__ a_src,
                            const float* __restrict__ a_dst,
                            uint2* __restrict__ hbufB,
                            float4* __restrict__ asrc4,
                            float4* __restrict__ adst4, int N) {
    __shared__ float xrow[NPB][64];
    __shared__ float trow[NPB][HC];
    __shared__ float sred[NPB][2][HEADS];
    int t = threadIdx.x;
    int base = blockIdx.x * NPB;
    for (int i = t; i < NPB * K; i += 256) {
        int nb = i / K, k = i - nb * K;
        int n = base + nb;
        if (n < N) xrow[nb][k] = in[(size_t)n * K + k];
    }
    __syncthreads();
    float acc[NPB];
#pragma unroll
    for (int nb = 0; nb < NPB; ++nb) acc[nb] = 0.f;
    for (int k = 0; k < K; ++k) {
        float w = W[k * HC + t];
#pragma unroll
        for (int nb = 0; nb < NPB; ++nb) acc[nb] += xrow[nb][k] * w;
    }
    int head = t >> 6, lane = t & 63;
    float aw_s = a_src[t], aw_d = a_dst[t];
#pragma unroll
    for (int nb = 0; nb < NPB; ++nb) {
        trow[nb][t] = acc[nb];
        float vs = acc[nb] * aw_s, vd = acc[nb] * aw_d;
        for (int off = 32; off; off >>= 1) {
            vs += __shfl_down(vs, off);
            vd += __shfl_down(vd, off);
        }
        if (lane == 0) { sred[nb][0][head] = vs; sred[nb][1][head] = vd; }
    }
    __syncthreads();
    for (int i = t; i < NPB * CH; i += 256) {
        int nb = i >> 6, c = i & 63;
        int n = base + nb;
        if (n < N) {
            uint2 p;
            p.x = f2bf(trow[nb][c])       | (f2bf(trow[nb][64 + c])  << 16);
            p.y = f2bf(trow[nb][128 + c]) | (f2bf(trow[nb][192 + c]) << 16);
            hbufB[(size_t)n * CH + c] = p;
        }
    }
    if (t < NPB) {
        int n = base + t;
        if (n < N) {
            asrc4[n] = make_float4(sred[t][0][0], sred[t][0][1],
                                   sred[t][0][2], sred[t][0][3]);
            adst4[n] = make_float4(sred[t][1][0], sred[t][1][1],
                                   sred[t][1][2], sred[t][1][3]);
        }
    }
}

// ---------------------------------------------------------------------------
// CSR build (once per call; graph shared by all 3 layers)
__global__ void count_kernel(const int* __restrict__ dst, int E, int N,
                             int* __restrict__ deg) {
    int e = blockIdx.x * blockDim.x + threadIdx.x;
    if (e >= E + N) return;
    int d = (e < E) ? dst[e] : e - E;
    atomicAdd(&deg[d], 1);
}

__global__ void scan_blocks(const int* __restrict__ deg,
                            int* __restrict__ off,
                            int* __restrict__ bsum, int N) {
    __shared__ int sh[256];
    int t = threadIdx.x;
    int g = blockIdx.x * 256 + t;
    int v = (g < N) ? deg[g] : 0;
    sh[t] = v;
    __syncthreads();
    for (int d = 1; d < 256; d <<= 1) {
        int x = (t >= d) ? sh[t - d] : 0;
        __syncthreads();
        sh[t] += x;
        __syncthreads();
    }
    if (g < N) off[g] = sh[t] - v;
    if (t == 255) bsum[blockIdx.x] = sh[255];
}

__global__ void scan_bsums(int* __restrict__ bsum, int G,
                           int* __restrict__ total_out) {
    __shared__ int sh[256];
    int t = threadIdx.x;
    int chunk = (G + 255) / 256;
    int lo = t * chunk, hi = min(lo + chunk, G);
    int s = 0;
    for (int i = lo; i < hi; ++i) s += bsum[i];
    sh[t] = s;
    __syncthreads();
    for (int d = 1; d < 256; d <<= 1) {
        int x = (t >= d) ? sh[t - d] : 0;
        __syncthreads();
        sh[t] += x;
        __syncthreads();
    }
    int run = (t > 0) ? sh[t - 1] : 0;
    for (int i = lo; i < hi; ++i) { int v = bsum[i]; bsum[i] = run; run += v; }
    if (t == 255) *total_out = sh[255];
}

__global__ void scan_add(int* __restrict__ off, const int* __restrict__ bsum,
                         int N) {
    int g = blockIdx.x * 256 + threadIdx.x;
    if (g < N) off[g] += bsum[blockIdx.x];
}

__global__ void scatter_kernel(const int* __restrict__ src,
                               const int* __restrict__ dst, int E, int N,
                               const int* __restrict__ off,
                               int* __restrict__ cursor,
                               int* __restrict__ csr_src) {
    int e = blockIdx.x * blockDim.x + threadIdx.x;
    if (e >= E + N) return;
    int s, d;
    if (e < E) { s = src[e]; d = dst[e]; } else { s = d = e - E; }
    int p = atomicAdd(&cursor[d], 1);
    csr_src[off[d] + p] = s;
}

// ---------------------------------------------------------------------------
// Fused softmax + aggregation (layers 2/3): one wave per dst node.
__global__ void node_fused_kernel(const int* __restrict__ off,
                                  const int* __restrict__ csr_src,
                                  const float4* __restrict__ asrc4,
                                  const float4* __restrict__ adst4,
                                  const uint2* __restrict__ hbufB,
                                  const float* __restrict__ b,
                                  const float* __restrict__ residual,
                                  const float* __restrict__ lin_w,
                                  const float* __restrict__ lin_b,
                                  float* __restrict__ out, int N) {
    int node = (blockIdx.x * blockDim.x + threadIdx.x) >> 6;
    int lane = threadIdx.x & 63;
    if (node >= N) return;
    int o0 = off[node], o1 = off[node + 1];
    int deg = o1 - o0;
    float4 ad = adst4[node];

    float l0 = 0.f, l1 = 0.f, l2 = 0.f, l3 = 0.f;
    float a0 = 0.f, a1 = 0.f, a2 = 0.f, a3 = 0.f;

    for (int base = 0; base < deg; base += 64) {
        int i = base + lane;
        int s = 0;
        float4 ev = make_float4(-INFINITY, -INFINITY, -INFINITY, -INFINITY);
        if (i < deg) {
            s = csr_src[o0 + i];
            float4 as = asrc4[s];
            ev.x = lrelu(as.x + ad.x);
            ev.y = lrelu(as.y + ad.y);
            ev.z = lrelu(as.z + ad.z);
            ev.w = lrelu(as.w + ad.w);
        }
        float4 ex;
        ex.x = __expf(ev.x);
        ex.y = __expf(ev.y);
        ex.z = __expf(ev.z);
        ex.w = __expf(ev.w);
        float4 ls = wave_sum4(ex);
        l0 += ls.x; l1 += ls.y; l2 += ls.z; l3 += ls.w;

        int cnt = min(64, deg - base);
#pragma unroll 4
        for (int e = 0; e < cnt; ++e) {
            int se = __shfl(s, e);
            float w0 = __shfl(ex.x, e);
            float w1 = __shfl(ex.y, e);
            float w2 = __shfl(ex.z, e);
            float w3 = __shfl(ex.w, e);
            uint2 h = hbufB[(size_t)se * CH + lane];
            float h0 = __uint_as_float(h.x << 16);
            float h1 = __uint_as_float(h.x & 0xFFFF0000u);
            float h2 = __uint_as_float(h.y << 16);
            float h3 = __uint_as_float(h.y & 0xFFFF0000u);
            a0 += h0 * w0; a1 += h1 * w1;
            a2 += h2 * w2; a3 += h3 * w3;
        }
    }

    float v = (a0 / l0 + a1 / l1 + a2 / l2 + a3 / l3) * 0.25f + b[lane];
    v = v > 0.f ? v : expm1f(v);
    if (residual) v += residual[(size_t)node * CH + lane];
    if (!lin_w) {
        out[(size_t)node * CH + lane] = v;
    } else {
        float t = v * lin_w[lane];
#pragma unroll
        for (int m = 32; m; m >>= 1) t += __shfl_xor(t, m);
        if (lane == 0) out[node] = t + lin_b[0];
    }
}

// ---------------------------------------------------------------------------
extern "C" void kernel_launch(void* const* d_in, const int* in_sizes, int n_in,
                              void* d_out, int out_size, void* d_ws, size_t ws_size,
                              hipStream_t stream) {
    const float* x      = (const float*)d_in[0];
    const int*   ei     = (const int*)  d_in[1];
    const float* W1     = (const float*)d_in[2];
    const float* a1s    = (const float*)d_in[3];
    const float* a1d    = (const float*)d_in[4];
    const float* b1     = (const float*)d_in[5];
    const float* W2     = (const float*)d_in[6];
    const float* a2s    = (const float*)d_in[7];
    const float* a2d    = (const float*)d_in[8];
    const float* b2     = (const float*)d_in[9];
    const float* W3     = (const float*)d_in[10];
    const float* a3s    = (const float*)d_in[11];
    const float* a3d    = (const float*)d_in[12];
    const float* b3     = (const float*)d_in[13];
    const float* lin_w  = (const float*)d_in[14];
    const float* lin_b  = (const float*)d_in[15];

    const int N = in_sizes[0] / 3;
    const int E = in_sizes[1] / 2;
    const int Et = E + N;
    const int* src = ei;
    const int* dst = ei + E;

    float* ws    = (float*)d_ws;
    uint2* hbufB = (uint2*)ws;                       // N*64 uint2 (bf16 x4)
    float* asrc  = ws     + (size_t)N * 128;         // N*4
    float* adst  = asrc   + (size_t)N * HEADS;       // N*4
    float* bufA  = adst   + (size_t)N * HEADS;       // N*64 (h1)
    float* bufB  = bufA   + (size_t)N * CH;          // N*64 (h2)
    int*   deg    = (int*)(bufB + (size_t)N * CH);   // N
    int*   cursor = deg    + N;                      // N (adjacent: one memset)
    int*   off    = cursor + N;                      // N+4 (padded for alignment)
    int*   bsum   = off    + N + 4;                  // 256
    int*   csr_src= bsum   + 256;                    // Et
    float* zl     = (float*)(csr_src + ((Et + 3) & ~3)); // N*16 (16B aligned)
    float* ws1    = zl     + (size_t)N * 16;         // 16
    float* wd1    = ws1    + 16;                     // 16

    const int B = 256;
    const int G = (N + 255) / 256;

    // ---- CSR build (once; shared by all 3 layers) ----
    hipMemsetAsync(deg, 0, (size_t)2 * N * sizeof(int), stream);  // deg+cursor
    count_kernel<<<(Et + B - 1) / B, B, 0, stream>>>(dst, E, N, deg);
    scan_blocks<<<G, B, 0, stream>>>(deg, off, bsum, N);
    scan_bsums<<<1, B, 0, stream>>>(bsum, G, off + N);
    scan_add<<<G, B, 0, stream>>>(off, bsum, N);
    scatter_kernel<<<(Et + B - 1) / B, B, 0, stream>>>(src, dst, E, N, off,
                                                       cursor, csr_src);

    int nwave_blocks = (N * 64 + B - 1) / B;   // wave per node

    // ---- Layer 1: input-space aggregation (x is 3-dim) ----
    proj_kernel<<<1, 64, 0, stream>>>(W1, a1s, a1d, 3, ws1, wd1);
    logits1_kernel<<<(N + B - 1) / B, B, 0, stream>>>(
        x, ws1, wd1, (float4*)asrc, (float4*)adst, N);
    fused1_kernel<<<nwave_blocks, B, 0, stream>>>(
        off, csr_src, x, (const float4*)asrc, (const float4*)adst,
        (float4*)zl, N);
    epi1_kernel<<<nwave_blocks, B, 0, stream>>>(
        (const float4*)zl, W1, b1, bufA, N);

    // ---- Layers 2/3: message-space aggregation (bf16 packed messages) ----
    auto run_layer = [&](const float* inp, const float* W,
                         const float* as, const float* ad, const float* bb,
                         const float* residual, const float* lw,
                         const float* lb, float* outbuf) {
        feat_kernel<<<(N + NPB - 1) / NPB, B, 0, stream>>>(
            inp, 64, W, as, ad, hbufB, (float4*)asrc, (float4*)adst, N);
        node_fused_kernel<<<nwave_blocks, B, 0, stream>>>(
            off, csr_src, (const float4*)asrc, (const float4*)adst,
            hbufB, bb, residual, lw, lb, outbuf, N);
    };

    run_layer(bufA, W2, a2s, a2d, b2, bufA, nullptr, nullptr, bufB);
    // layer 3: fused final linear writes d_out[N] directly
    run_layer(bufB, W3, a3s, a3d, b3, bufB, lin_w, lin_b, (float*)d_out);
}